// Round 8
// baseline (517.527 us; speedup 1.0000x reference)
//
#include <hip/hip_runtime.h>
#include <stdint.h>

#define N 8192
#define D 256

typedef __attribute__((ext_vector_type(4))) float f32x4;
typedef __attribute__((ext_vector_type(8))) short bf16x8;

__device__ __forceinline__ unsigned short f2bf(float f) {
    unsigned u = __float_as_uint(f);
    u += 0x7fff + ((u >> 16) & 1);           // RNE
    return (unsigned short)(u >> 16);
}
__device__ __forceinline__ float bf2f(unsigned short h) {
    return __uint_as_float(((unsigned)h) << 16);
}
__device__ __forceinline__ float leaky(float x) {
    return fmaxf(x, 0.f) + 0.2f * fminf(x, 0.f);
}
// Monotonic float<->uint key for atomicMax on float values
__device__ __forceinline__ unsigned fkey(float f) {
    unsigned b = __float_as_uint(f);
    return (b & 0x80000000u) ? ~b : (b | 0x80000000u);
}
__device__ __forceinline__ float fkey_dec(unsigned k) {
    unsigned b = (k & 0x80000000u) ? (k ^ 0x80000000u) : ~k;
    return __uint_as_float(b);
}
// CK-style block_sync_lds: LDS-ordering barrier that does NOT drain vmcnt.
__device__ __forceinline__ void sync_lds() {
    asm volatile("s_waitcnt lgkmcnt(0)\n\ts_barrier" ::: "memory");
}

// ---------------- PREP: (a) compress adj+diag into bitmask, (b) W transpose/split, (c) init maxkey ----
#define NB_MASK (N * N / 4 / 256)    // 65536 blocks for mask part
__global__ __launch_bounds__(256) void kprep(const float* __restrict__ adj,
                                             unsigned int* __restrict__ mask,
                                             const float* __restrict__ W,
                                             unsigned short* __restrict__ wthi,
                                             unsigned short* __restrict__ wtlo,
                                             unsigned int* __restrict__ maxkey) {
    const int bid = blockIdx.x;
    if (bid < NB_MASK) {
        const size_t fbase = ((size_t)bid * 256 + threadIdx.x) * 4;  // float index
        float4 v = *(const float4*)(adj + fbase);
        const int lane = threadIdx.x & 63;
        unsigned nib = (v.x > 0.f ? 1u : 0u) | (v.y > 0.f ? 2u : 0u) |
                       (v.z > 0.f ? 4u : 0u) | (v.w > 0.f ? 8u : 0u);
        unsigned word = nib << ((lane & 7) * 4);
        word |= __shfl_xor(word, 1);
        word |= __shfl_xor(word, 2);
        word |= __shfl_xor(word, 4);
        if ((lane & 7) == 0) {
            size_t widx = fbase >> 5;
            int r = (int)(widx >> 8);
            int ww = (int)(widx & 255);
            if ((r >> 5) == ww) word |= 1u << (r & 31);   // diagonal
            mask[widx] = word;
        }
    } else {
        const int n = bid - NB_MASK;       // 0..255: output row of WT
        const int k = threadIdx.x;
        if (n == 0 && k == 0) *maxkey = 0u;   // below any real float key
        float w = W[(size_t)k * D + n];    // W[k][n]
        unsigned short h = f2bf(w);
        unsigned short l = f2bf(w - bf2f(h));
        wthi[(size_t)n * D + k] = h;
        wtlo[(size_t)n * D + k] = l;
    }
}

// ---------------- K1m: Wh = x@W via bf16x3 MFMA (x converted in-reg);
//                  writes WhT bf16, e_src/e_dst, atomicMax(maxkey) ----------------
__global__ __launch_bounds__(256) void k1m(const float* __restrict__ x,
                                           const unsigned short* __restrict__ wthi,
                                           const unsigned short* __restrict__ wtlo,
                                           const float* __restrict__ a,
                                           unsigned short* __restrict__ WhT,
                                           float* __restrict__ e_src,
                                           float* __restrict__ e_dst,
                                           unsigned int* __restrict__ maxkey) {
    __shared__ float obuf[16 * 256];   // 16 KB staging
    __shared__ float red[16];

    const int t = threadIdx.x;
    const int r0 = blockIdx.x * 16;
    const int w = t >> 6;              // 0..3
    const int lane = t & 63;
    const int quad = lane >> 4, lo = lane & 15;

    const float* x_row = x + (size_t)(r0 + lo) * D;

    f32x4 acc[4];
#pragma unroll
    for (int nt = 0; nt < 4; ++nt) acc[nt] = (f32x4){0.f, 0.f, 0.f, 0.f};

#pragma unroll
    for (int ks = 0; ks < 8; ++ks) {   // k chunks of 32
        const int kofs = ks * 32 + quad * 8;
        float4 v0 = *(const float4*)(x_row + kofs);
        float4 v1 = *(const float4*)(x_row + kofs + 4);
        float vv[8] = {v0.x, v0.y, v0.z, v0.w, v1.x, v1.y, v1.z, v1.w};
        bf16x8 ah, al;
#pragma unroll
        for (int j = 0; j < 8; ++j) {
            unsigned short h = f2bf(vv[j]);
            ah[j] = (short)h;
            al[j] = (short)f2bf(vv[j] - bf2f(h));
        }
#pragma unroll
        for (int nt = 0; nt < 4; ++nt) {
            const int n = w * 64 + nt * 16 + lo;
            bf16x8 bh = *(const bf16x8*)(wthi + (size_t)n * D + kofs);
            bf16x8 bl = *(const bf16x8*)(wtlo + (size_t)n * D + kofs);
            acc[nt] = __builtin_amdgcn_mfma_f32_16x16x32_bf16(ah, bh, acc[nt], 0, 0, 0);
            acc[nt] = __builtin_amdgcn_mfma_f32_16x16x32_bf16(ah, bl, acc[nt], 0, 0, 0);
            acc[nt] = __builtin_amdgcn_mfma_f32_16x16x32_bf16(al, bh, acc[nt], 0, 0, 0);
        }
    }

    // WhT bf16 [n][r]
#pragma unroll
    for (int nt = 0; nt < 4; ++nt) {
        const int n = w * 64 + nt * 16 + lo;
        unsigned short pk[4];
#pragma unroll
        for (int reg = 0; reg < 4; ++reg) pk[reg] = f2bf(acc[nt][reg]);
        *(ushort2*)(WhT + (size_t)n * N + r0 + quad * 4) = *(ushort2*)&pk[0];
        *(ushort2*)(WhT + (size_t)n * N + r0 + quad * 4 + 2) = *(ushort2*)&pk[2];
    }

    // stage 16x256 fp32 block to LDS for e-dots
#pragma unroll
    for (int nt = 0; nt < 4; ++nt) {
        const int col = w * 64 + nt * 16 + lo;
#pragma unroll
        for (int reg = 0; reg < 4; ++reg)
            obuf[(quad * 4 + reg) * 256 + col] = acc[nt][reg];
    }
    __syncthreads();

    // e_src/e_dst: row = t>>4, 16 threads per row, 16 cols each
    const int row = t >> 4;
    const int c0 = (t & 15) * 16;
    float ps = 0.f, pd = 0.f;
#pragma unroll
    for (int j = 0; j < 4; ++j) {
        float4 wv = *(const float4*)&obuf[row * 256 + c0 + j * 4];
        float4 as = *(const float4*)(a + c0 + j * 4);
        float4 ad = *(const float4*)(a + D + c0 + j * 4);
        ps += wv.x * as.x + wv.y * as.y + wv.z * as.z + wv.w * as.w;
        pd += wv.x * ad.x + wv.y * ad.y + wv.z * ad.z + wv.w * ad.w;
    }
#pragma unroll
    for (int msk = 1; msk < 16; msk <<= 1) {
        ps += __shfl_xor(ps, msk);
        pd += __shfl_xor(pd, msk);
    }
    if ((t & 15) == 0) {
        e_src[r0 + row] = ps;
        e_dst[r0 + row] = pd;
        red[row] = pd;
    }
    __syncthreads();
    if (t == 0) {
        float m = red[0];
#pragma unroll
        for (int i = 1; i < 16; ++i) m = fmaxf(m, red[i]);
        atomicMax(maxkey, fkey(m));
    }
}

// ---------------- K4: masked softmax + PV matmul (bitmask adj, BM=32, SPLITS=4) ----------------
#define BM 32
#define BK 64
#define RB (N / BM)                 // 256 row-blocks
#define SPLITS 4                    // grid = RB*SPLITS = 1024
#define NITER ((N / SPLITS) / BK)   // 32
#define PSTRIDE 72                  // ushorts per P row (144 B)
__global__ __launch_bounds__(512, 4) void k4_main(const unsigned char* __restrict__ mask,
                                                  const unsigned short* __restrict__ WhT,
                                                  const float* __restrict__ e_src,
                                                  const float* __restrict__ e_dst,
                                                  const unsigned int* __restrict__ maxkey,
                                                  float* __restrict__ O_part,
                                                  float* __restrict__ l_part) {
    __shared__ char smem[16 * 256 * 4];   // 16 KB: P tiles (9 KB) in loop, obuf in epilogue
    typedef unsigned short pbuf_t[BM][PSTRIDE];
    pbuf_t* p_lds = (pbuf_t*)smem;        // p_lds[2][32][72]

    const int t = threadIdx.x;
    const int rb = blockIdx.x & (RB - 1);
    const int s  = blockIdx.x >> 8;          // RB = 256
    const int r0 = rb * BM;
    const int j0 = s * (N / SPLITS);

    // P-generation coords: 16 threads per row, 4 cols each
    const int pr = t >> 4;            // 0..31
    const int pcl = t & 15;
    const int pc = pcl * 4;           // 0..60
    const int gr = r0 + pr;

    const int w = t >> 6;             // wave 0..7 -> output cols w*32..w*32+31
    const int lane = t & 63;
    const int quad = lane >> 4, lo = lane & 15;

    const float md = fkey_dec(*maxkey);
    const float es = e_src[gr];
    const float m = leaky(es + md);

    f32x4 acc[2][2];
#pragma unroll
    for (int mt = 0; mt < 2; ++mt)
#pragma unroll
        for (int nt = 0; nt < 2; ++nt)
            acc[mt][nt] = (f32x4){0.f, 0.f, 0.f, 0.f};
    float lsum = 0.f;

    // mask row slice: 256 B per (row, split); this thread's byte for iter it
    // is mrow[it*8] (pcl>>1 folded into base); nibble = pcl&1.
    const unsigned char* mrow = mask + (size_t)gr * (N / 8) + (j0 >> 3) + (pcl >> 1);
    const int nsh = (pcl & 1) * 4;
    const float* ed_row = e_dst + j0 + pc;
    const unsigned short* wt_base = WhT + (size_t)(w * 32 + lo) * N + j0 + quad * 8;

    unsigned int mb;
    float4 edv;
    bf16x8 bfr[2][2];                 // [ks2][nt]

    // ---- prologue: loads for tile 0 ----
    mb = mrow[0];
    edv = *(const float4*)(ed_row);
#pragma unroll
    for (int ks2 = 0; ks2 < 2; ++ks2)
#pragma unroll
        for (int nt = 0; nt < 2; ++nt)
            bfr[ks2][nt] = *(const bf16x8*)(wt_base + (size_t)nt * (16 * N) + ks2 * 32);

    auto stage = [&](int buf) {
        float ev[4] = {edv.x, edv.y, edv.z, edv.w};
        unsigned nib = (mb >> nsh) & 0xFu;
        unsigned short pk[4];
#pragma unroll
        for (int jj = 0; jj < 4; ++jj) {
            float e = leaky(es + ev[jj]);
            float p = ((nib >> jj) & 1u) ? __expf(e - m) : 0.f;
            lsum += p;
            pk[jj] = f2bf(p);
        }
        *(ushort4*)&p_lds[buf][pr][pc] = *(ushort4*)pk;
    };

    stage(0);
    mb = mrow[8];
    edv = *(const float4*)(ed_row + BK);
    sync_lds();

#pragma unroll 2
    for (int it = 0; it < NITER; ++it) {
        const int cb = it & 1, nb = cb ^ 1;

        // ---- MFMA on p_lds[cb] x bfr ----
#pragma unroll
        for (int ks2 = 0; ks2 < 2; ++ks2) {
            bf16x8 afr[2];
#pragma unroll
            for (int mt = 0; mt < 2; ++mt)
                afr[mt] = *(const bf16x8*)&p_lds[cb][mt * 16 + lo][ks2 * 32 + quad * 8];
#pragma unroll
            for (int nt = 0; nt < 2; ++nt)
#pragma unroll
                for (int mt = 0; mt < 2; ++mt)
                    acc[mt][nt] = __builtin_amdgcn_mfma_f32_16x16x32_bf16(
                        afr[mt], bfr[ks2][nt], acc[mt][nt], 0, 0, 0);
        }

        // ---- reissue B-fragment loads for it+1 (stay in flight across barrier) ----
        {
            const int itn = (it + 1 < NITER) ? it + 1 : NITER - 1;
#pragma unroll
            for (int ks2 = 0; ks2 < 2; ++ks2)
#pragma unroll
                for (int nt = 0; nt < 2; ++nt)
                    bfr[ks2][nt] = *(const bf16x8*)(wt_base + (size_t)nt * (16 * N) +
                                                    itn * BK + ks2 * 32);
        }

        // ---- stage(it+1) into p_lds[nb], prefetch mask/ed for it+2 ----
        if (it + 1 < NITER) {
            stage(nb);
            const int itn2 = (it + 2 < NITER) ? it + 2 : NITER - 1;
            mb = mrow[itn2 * 8];
            edv = *(const float4*)(ed_row + itn2 * BK);
        }
        sync_lds();
    }

    // ---- epilogue: reduce per-row partial l (16 threads per row) ----
#pragma unroll
    for (int msk = 1; msk < 16; msk <<= 1) lsum += __shfl_xor(lsum, msk);
    if ((t & 15) == 0) l_part[(size_t)s * N + gr] = lsum;

    // ---- epilogue: O_part via LDS transpose -> coalesced float4 stores ----
    float* obuf = (float*)smem;
#pragma unroll
    for (int mt = 0; mt < 2; ++mt) {
        __syncthreads();
#pragma unroll
        for (int nt = 0; nt < 2; ++nt) {
            f32x4 v = acc[mt][nt];
            int col = w * 32 + nt * 16 + lo;
#pragma unroll
            for (int reg = 0; reg < 4; ++reg)
                obuf[(quad * 4 + reg) * 256 + col] = v[reg];
        }
        __syncthreads();
        const int orow = t >> 5;            // 0..15
        const int ocol = (t & 31) * 8;      // 0..248
        f32x4 o0 = *(const f32x4*)&obuf[orow * 256 + ocol];
        f32x4 o1 = *(const f32x4*)&obuf[orow * 256 + ocol + 4];
        float* dst = O_part + ((size_t)s * N + r0 + mt * 16 + orow) * D + ocol;
        *(f32x4*)dst = o0;
        *(f32x4*)(dst + 4) = o1;
    }
}

// ---------------- K5: reduce partials (float4), divide by l ----------------
__global__ __launch_bounds__(256) void k5_reduce(const float* __restrict__ O_part,
                                                 const float* __restrict__ l_part,
                                                 float* __restrict__ out) {
    const int idx = blockIdx.x * 256 + threadIdx.x;   // over N*D/4
    const int r = idx >> 6;
    float lsum = 0.f;
#pragma unroll
    for (int s = 0; s < SPLITS; ++s) lsum += l_part[(size_t)s * N + r];
    f32x4 o = (f32x4){0.f, 0.f, 0.f, 0.f};
#pragma unroll
    for (int s = 0; s < SPLITS; ++s)
        o += *(const f32x4*)(O_part + (size_t)s * N * D + (size_t)idx * 4);
    const float inv = 1.f / lsum;
    *(f32x4*)(out + (size_t)idx * 4) = o * inv;
}

// ---------------- launch ----------------
extern "C" void kernel_launch(void* const* d_in, const int* in_sizes, int n_in,
                              void* d_out, int out_size, void* d_ws, size_t ws_size,
                              hipStream_t stream) {
    const float* x   = (const float*)d_in[0];   // [N, D]
    const float* adj = (const float*)d_in[1];   // [N, N]
    const float* W   = (const float*)d_in[2];   // [D, D]
    const float* a   = (const float*)d_in[3];   // [2*D]
    float* out = (float*)d_out;

    // ws layout (~48 MB):
    char* ws = (char*)d_ws;
    unsigned short* WhT  = (unsigned short*)(ws);                // 4 MB
    unsigned short* wthi = (unsigned short*)(ws + 4194304);      // 128 KB
    unsigned short* wtlo = (unsigned short*)(ws + 4325376);      // 128 KB
    float* e_src         = (float*)(ws + 4456448);               // 32 KB
    float* e_dst         = (float*)(ws + 4489216);               // 32 KB
    unsigned int* maxkey = (unsigned int*)(ws + 4521984);        // 256 B
    float* l_part        = (float*)(ws + 4522240);               // 128 KB (SPLITS*N*4)
    unsigned int* mask   = (unsigned int*)(ws + 8388608);        // 8 MB (N*N/8 bytes)
    float* O_part        = (float*)(ws + 16777216);              // 32 MB (SPLITS*N*D*4)

    kprep<<<NB_MASK + D, 256, 0, stream>>>(adj, mask, W, wthi, wtlo, maxkey);
    k1m<<<N / 16, 256, 0, stream>>>(x, wthi, wtlo, a, WhT, e_src, e_dst, maxkey);
    k4_main<<<RB * SPLITS, 512, 0, stream>>>((const unsigned char*)mask, WhT, e_src, e_dst,
                                             maxkey, O_part, l_part);
    k5_reduce<<<N * D / 4 / 256, 256, 0, stream>>>(O_part, l_part, out);
}